// Round 21
// baseline (162.552 us; speedup 1.0000x reference)
//
#include <hip/hip_runtime.h>

// Branch MLP: B=16384 rows, E=4 experts, 512->1024->1024->512, relu/relu/tanh.
// Bucket rows by expert, pad segments to 128-row granularity w/ duplicate
// rows, 3 bf16-MFMA GEMM passes. Weights pre-transposed bf16 [E][N][K]; x
// pre-gathered to permuted bf16 xp. GEMM: single-buffer 2-barrier loop,
// chunk-XOR LDS swizzle + bijective chunked XCD swizzle.
// R21: gemm2/gemm3 use BM=64 x BN=128 (24KB LDS -> 6 blocks/CU, 2112/1056
// blocks) from a 64-row tile list — R17's winning +TLP lever applied to both
// K=1024 GEMMs. gemm1 keeps the 128x128 shape (NK=8, already ~26us).
//
// Workspace (86.1 MB):
//   ctrl[64] | t64E[264]@+64 | t64B[264]@+384 | t128E[136]@+704 |
//   t128B[136]@+896 | perm[16896]@+1088 (ends < 128KB)
//   Wt1 (4.19MB) | Wt2 (8.39MB) | Wt3 (4.19MB) | h1 (34.6MB) | h2 (34.6MB)
//   xp (17.3MB) aliases h2 (xp dead before gemm2 writes h2).

#define B_N   16384
#define DIN   512
#define HID   1024
#define DOUT  512
#define MAXT128 136
#define MAXT64  264

typedef __attribute__((ext_vector_type(8))) short bf16x8;
typedef __attribute__((ext_vector_type(4))) float f32x4;
typedef __attribute__((address_space(3))) unsigned int lds_u32;
typedef const __attribute__((address_space(1))) unsigned int glb_u32;

__device__ __forceinline__ void gll16(const void* g, void* l) {
    __builtin_amdgcn_global_load_lds((glb_u32*)g, (lds_u32*)l, 16, 0, 0);
}

__device__ __forceinline__ unsigned short f2bf(float f) {
    unsigned int u = __float_as_uint(f);
    u += 0x7FFFu + ((u >> 16) & 1u);   // RNE
    return (unsigned short)(u >> 16);
}

__device__ __forceinline__ float fast_tanh(float x) {
    x = fminf(fmaxf(x, -9.0f), 9.0f);
    float t = __builtin_amdgcn_exp2f(x * 2.8853900817779268f);
    return (t - 1.0f) * __builtin_amdgcn_rcpf(t + 1.0f);
}

__global__ void zero_k(int* __restrict__ ctrl) {
    if (threadIdx.x < 16) ctrl[threadIdx.x] = 0;
}

// Parallel histogram: wave-aggregated, 4 atomics/wave max.
__global__ void count_k(const int* __restrict__ cmd, int* __restrict__ ctrl) {
    int i = blockIdx.x * 256 + threadIdx.x;
    int e = cmd[i] & 3;
    int lane = threadIdx.x & 63;
#pragma unroll
    for (int ee = 0; ee < 4; ++ee) {
        unsigned long long mask = __ballot(e == ee);
        int leader = __ffsll((unsigned long long)mask) - 1;
        if (mask && lane == leader)
            atomicAdd(&ctrl[ee], __popcll(mask));
    }
}

// Tiny: build BOTH tile plans (128-row for gemm1, 64-row for gemm2/3) +
// segment bases + zero scatter cursors. Padding stays 128-granular, so
// every 64-row tile is full.
__global__ void plan_k(int* __restrict__ ctrl,
                       int* __restrict__ t64E, int* __restrict__ t64B,
                       int* __restrict__ t128E, int* __restrict__ t128B) {
    if (threadIdx.x == 0) {
        int P = 0, n128 = 0, n64 = 0;
        for (int e = 0; e < 4; ++e) {
            ctrl[4 + e] = 0;          // scatter cursors
            ctrl[8 + e] = P;
            int t128 = (ctrl[e] + 127) >> 7;
            for (int t = 0; t < t128; ++t) {
                t128E[n128] = e; t128B[n128] = P + t * 128; ++n128;
            }
            for (int t = 0; t < t128 * 2; ++t) {
                t64E[n64] = e; t64B[n64] = P + t * 64; ++n64;
            }
            P += t128 * 128;
        }
        ctrl[12] = P;                 // total padded rows
        ctrl[13] = n128;              // 128-row tiles (<= 132)
        ctrl[14] = n64;               // 64-row tiles (<= 264)
    }
}

// Wave-aggregated scatter: one atomicAdd(popcount) per wave per expert.
__global__ void scatter_k(const int* __restrict__ cmd, int* __restrict__ ctrl,
                          int* __restrict__ perm) {
    int i = blockIdx.x * 256 + threadIdx.x;
    int e = cmd[i] & 3;
    int lane = threadIdx.x & 63;
#pragma unroll
    for (int ee = 0; ee < 4; ++ee) {
        unsigned long long mask = __ballot(e == ee);
        if (e == ee) {
            int leader = __ffsll((unsigned long long)mask) - 1;
            int rank = __popcll(mask & ((1ull << lane) - 1ull));
            int wbase = 0;
            if (lane == leader)
                wbase = atomicAdd(&ctrl[4 + ee], __popcll(mask));
            wbase = __builtin_amdgcn_readfirstlane(wbase);
            perm[ctrl[8 + ee] + wbase + rank] = i;
        }
    }
}

// Fused prep: blocks [0,8192) transpose+convert weights (packed uint writes);
// blocks [8192,12416) gather x -> permuted bf16 xp and fill pad perm entries.
__global__ __launch_bounds__(256) void prep_data_k(
    const float* __restrict__ W1, const float* __restrict__ W2,
    const float* __restrict__ W3, unsigned short* __restrict__ Wt1,
    unsigned short* __restrict__ Wt2, unsigned short* __restrict__ Wt3,
    const float* __restrict__ x, unsigned short* __restrict__ xp,
    int* __restrict__ perm, const int* __restrict__ ctrl)
{
    int b = blockIdx.x;
    if (b < 8192) {
        int e = b >> 11, r = b & 2047;
        const float* W; unsigned short* Wt; int KD, ND, kt, nt;
        if (r < 512)       { W = W1; Wt = Wt1; KD = 512;  ND = 1024; kt = r & 15;           nt = r >> 4; }
        else if (r < 1536) { W = W2; Wt = Wt2; KD = 1024; ND = 1024; kt = (r - 512) & 31;   nt = (r - 512) >> 5; }
        else               { W = W3; Wt = Wt3; KD = 1024; ND = 512;  kt = (r - 1536) & 31;  nt = (r - 1536) >> 5; }
        __shared__ float t[32][33];
        size_t base = (size_t)e * KD * ND;
        int k0 = kt * 32, n0 = nt * 32;
        int tx = threadIdx.x & 31, ty = threadIdx.x >> 5;
#pragma unroll
        for (int s = 0; s < 4; ++s)
            t[ty + s * 8][tx] = W[base + (size_t)(k0 + ty + s * 8) * ND + n0 + tx];
        __syncthreads();
        int tx2 = (threadIdx.x & 15) * 2, ny = threadIdx.x >> 4;
#pragma unroll
        for (int s = 0; s < 2; ++s) {
            int n = ny + s * 16;
            unsigned int v = (unsigned)f2bf(t[tx2][n])
                           | ((unsigned)f2bf(t[tx2 + 1][n]) << 16);
            *(unsigned int*)&Wt[base + (size_t)(n0 + n) * KD + k0 + tx2] = v;
        }
    } else {
        int g = b - 8192;
        int p = g * 4 + (int)(threadIdx.x >> 6);
        if (p >= ctrl[12]) return;
        int lane = threadIdx.x & 63;
        int e = (p >= ctrl[9]) + (p >= ctrl[10]) + (p >= ctrl[11]);
        int segBase = ctrl[8 + e];
        int src;
        if (p < segBase + ctrl[e]) {
            src = perm[p];
        } else {
            src = perm[segBase];              // duplicate a valid same-expert row
            if (lane == 0) perm[p] = src;     // so gemm3 scatter-epilogue is safe
        }
        const float* xr = x + (size_t)src * DIN + lane * 8;
        float4 a = *(const float4*)xr;
        float4 c = *(const float4*)(xr + 4);
        uint4 o;
        o.x = (unsigned)f2bf(a.x) | ((unsigned)f2bf(a.y) << 16);
        o.y = (unsigned)f2bf(a.z) | ((unsigned)f2bf(a.w) << 16);
        o.z = (unsigned)f2bf(c.x) | ((unsigned)f2bf(c.y) << 16);
        o.w = (unsigned)f2bf(c.z) | ((unsigned)f2bf(c.w) << 16);
        *(uint4*)(xp + (size_t)p * DIN + lane * 8) = o;
    }
}

// Grouped GEMM: C = act(A @ Wt[e]^T + b[e]). BM/BN template, BK=64, 256 thr
// = 4 waves (2x2 quadrants: wave tile (BM/2) x (BN/2); MI=BM/32, NI=BN/32
// 16x16x32 frags, 2 k-halves). Single buffer, 2 barriers per K-step.
// Chunk-XOR involution: LDS slot s of row r holds global 16B-chunk
// (s ^ (r&7)); ds_read XORs the same (call bases are 32-row multiples so
// row&7 == tr&7). gll16 LDS dest stays tid*16B-linear per call.
// Chunked XCD swizzle: grid = NTILES*PN (divisible by 8), XCD x covers
// tiles [CH*x, CH*(x+1)) x all panels, CH = NTILES/8.
template<int K, int N, int BM, int BN, int NTILES, int PN, int CIDX,
         int ACT, bool SCATTER_OUT>
__global__ __launch_bounds__(256) void gemm_k(
    const unsigned short* __restrict__ A, const unsigned short* __restrict__ Bt,
    const float* __restrict__ bias, void* __restrict__ Outp,
    const int* __restrict__ ctrl, const int* __restrict__ tileExpert,
    const int* __restrict__ tileBase, const int* __restrict__ perm)
{
    constexpr int MI = BM / 32;               // A frags per wave (4 or 2)
    constexpr int NI = BN / 32;               // B frags per wave (4)
    constexpr int ACALLS = BM / 32;
    constexpr int BCALLS = BN / 32;
    const int l = (int)blockIdx.x + NTILES * (int)blockIdx.y;
    const int swz = (l & 7) * ((NTILES / 8) * PN) + (l >> 3);
    const int tile = swz / PN;                // PN pow2 -> shift
    const int panel = swz & (PN - 1);
    if (tile >= ctrl[CIDX]) return;
    const int e = tileExpert[tile];
    const int rowBase = tileBase[tile];
    const int n0 = panel * BN;

    __shared__ unsigned short Als[BM * 64];   // 16 or 8 KB
    __shared__ unsigned short Bls[BN * 64];   // 16 KB

    const int tid = threadIdx.x;
    const int lane = tid & 63;
    const int w = tid >> 6;
    const int wm = w >> 1, wn = w & 1;
    const int lr = lane & 15, lh = lane >> 4;

    f32x4 acc[MI][NI] = {};

    // Staging: thread t -> row tr (within 32-row call-block), chunk-slot tc.
    const int tr = tid >> 3;                  // 0..31
    const int tc = tid & 7;                   // chunk slot 0..7
    const int cs = (tc ^ (tr & 7)) * 8;       // source ushort offset in row
    const unsigned short* As = A + (size_t)(rowBase + tr) * K + cs;
    const unsigned short* Bs = Bt + ((size_t)e * N + n0 + tr) * K + cs;
    const int ldst = tr * 64 + tc * 8;        // ushort idx; byte == tid*16

    constexpr int NK = K / 64;
    for (int kq = 0; kq < NK; ++kq) {
        const int k0 = kq * 64;
        __syncthreads();                      // prior reads of buffer done
#pragma unroll
        for (int j = 0; j < ACALLS; ++j)
            gll16(As + (size_t)(j * 32) * K + k0, &Als[j * 2048 + ldst]);
#pragma unroll
        for (int j = 0; j < BCALLS; ++j)
            gll16(Bs + (size_t)(j * 32) * K + k0, &Bls[j * 2048 + ldst]);
        __syncthreads();                      // drains vmcnt before release
#pragma unroll
        for (int kk = 0; kk < 2; ++kk) {
            const int ksl = ((kk * 4 + lh) ^ (lr & 7)) * 8;   // swizzled read
            bf16x8 afr[MI], bfr[NI];
#pragma unroll
            for (int mi = 0; mi < MI; ++mi)
                afr[mi] = *(const bf16x8*)&Als[(wm * (BM / 2) + mi * 16 + lr) * 64 + ksl];
#pragma unroll
            for (int ni = 0; ni < NI; ++ni)
                bfr[ni] = *(const bf16x8*)&Bls[(wn * (BN / 2) + ni * 16 + lr) * 64 + ksl];
#pragma unroll
            for (int mi = 0; mi < MI; ++mi)
#pragma unroll
                for (int ni = 0; ni < NI; ++ni)
                    acc[mi][ni] = __builtin_amdgcn_mfma_f32_16x16x32_bf16(
                        afr[mi], bfr[ni], acc[mi][ni], 0, 0, 0);
        }
    }

    float bv[NI];
    int colv[NI];
#pragma unroll
    for (int ni = 0; ni < NI; ++ni) {
        colv[ni] = n0 + wn * (BN / 2) + ni * 16 + lr;
        bv[ni] = bias[e * N + colv[ni]];
    }
#pragma unroll
    for (int mi = 0; mi < MI; ++mi) {
#pragma unroll
        for (int r = 0; r < 4; ++r) {
            int rowL = wm * (BM / 2) + mi * 16 + lh * 4 + r;  // C/D row map
            int gRow = rowBase + rowL;
            int orow = SCATTER_OUT ? perm[gRow] : gRow;
#pragma unroll
            for (int ni = 0; ni < NI; ++ni) {
                float v = acc[mi][ni][r] + bv[ni];
                if (ACT == 0) v = fmaxf(v, 0.0f);
                else          v = fast_tanh(v);
                if (SCATTER_OUT)
                    ((float*)Outp)[(size_t)orow * N + colv[ni]] = v;
                else
                    ((unsigned short*)Outp)[(size_t)orow * N + colv[ni]] = f2bf(v);
            }
        }
    }
}

extern "C" void kernel_launch(void* const* d_in, const int* in_sizes, int n_in,
                              void* d_out, int out_size, void* d_ws, size_t ws_size,
                              hipStream_t stream) {
    const float* x  = (const float*)d_in[0];
    const int*   cmd= (const int*)d_in[1];
    const float* W1 = (const float*)d_in[2];
    const float* b1 = (const float*)d_in[3];
    const float* W2 = (const float*)d_in[4];
    const float* b2 = (const float*)d_in[5];
    const float* W3 = (const float*)d_in[6];
    const float* b3 = (const float*)d_in[7];
    float* out = (float*)d_out;

    char* w = (char*)d_ws;
    int* ctrl  = (int*)w;
    int* t64E  = ctrl + 64;     // 264
    int* t64B  = ctrl + 384;    // 264
    int* t128E = ctrl + 704;    // 136
    int* t128B = ctrl + 896;    // 136
    int* perm  = ctrl + 1088;   // 16896 ints, ends < 128KB
    unsigned short* Wt1 = (unsigned short*)(w + 131072);
    unsigned short* Wt2 = (unsigned short*)(w + 131072 + 4194304);
    unsigned short* Wt3 = (unsigned short*)(w + 131072 + 12582912);
    unsigned short* h1  = (unsigned short*)(w + 131072 + 16777216);
    unsigned short* h2  = h1 + (size_t)16896 * HID;       // 34.6 MB each
    unsigned short* xp  = h2;                             // aliases h2 (WAR-safe)

    zero_k<<<1, 64, 0, stream>>>(ctrl);
    count_k<<<B_N / 256, 256, 0, stream>>>(cmd, ctrl);
    plan_k<<<1, 64, 0, stream>>>(ctrl, t64E, t64B, t128E, t128B);
    scatter_k<<<B_N / 256, 256, 0, stream>>>(cmd, ctrl, perm);
    prep_data_k<<<8192 + 4224, 256, 0, stream>>>(W1, W2, W3, Wt1, Wt2, Wt3,
                                                 x, xp, perm, ctrl);

    // gemm1: 128x128 (NK=8, proven 26us shape)
    gemm_k<DIN, HID, 128, 128, MAXT128, 8, 13, 0, false>
        <<<dim3(MAXT128, 8), 256, 0, stream>>>(
        xp, Wt1, b1, h1, ctrl, t128E, t128B, perm);
    // gemm2: 64x128, 2112 blocks, 24KB LDS (6 blocks/CU)
    gemm_k<HID, HID, 64, 128, MAXT64, 8, 14, 0, false>
        <<<dim3(MAXT64, 8), 256, 0, stream>>>(
        h1, Wt2, b2, h2, ctrl, t64E, t64B, perm);
    // gemm3: 64x128, 1056 blocks, 24KB LDS
    gemm_k<HID, DOUT, 64, 128, MAXT64, 4, 14, 1, true>
        <<<dim3(MAXT64, 4), 256, 0, stream>>>(
        h2, Wt3, b3, out, ctrl, t64E, t64B, perm);
}

// Round 22
// 159.276 us; speedup vs baseline: 1.0206x; 1.0206x over previous
//
#include <hip/hip_runtime.h>

// Branch MLP: B=16384 rows, E=4 experts, 512->1024->1024->512, relu/relu/tanh.
// Bucket rows by expert, pad segments to 128-row granularity w/ duplicate
// rows, 3 bf16-MFMA GEMM passes. Weights pre-transposed bf16 [E][N][K]; x
// pre-gathered to permuted bf16 xp. GEMM: single-buffer 2-barrier loop,
// chunk-XOR LDS swizzle + bijective chunked XCD swizzle.
// R22: ALL three GEMMs use BM=64 x BN=128 (24KB LDS -> 6 blocks/CU) from the
// 64-row tile list — the R17/R21 +TLP lever (dispatch-verified: 51.5->47.2,
// occupancy 20->34%) applied uniformly.
//
// Workspace (86.1 MB):
//   ctrl[64] | t64E[264]@+64 | t64B[264]@+384 | t128E[136]@+704 |
//   t128B[136]@+896 | perm[16896]@+1088 (ends < 128KB)
//   Wt1 (4.19MB) | Wt2 (8.39MB) | Wt3 (4.19MB) | h1 (34.6MB) | h2 (34.6MB)
//   xp (17.3MB) aliases h2 (xp dead before gemm2 writes h2).

#define B_N   16384
#define DIN   512
#define HID   1024
#define DOUT  512
#define MAXT128 136
#define MAXT64  264

typedef __attribute__((ext_vector_type(8))) short bf16x8;
typedef __attribute__((ext_vector_type(4))) float f32x4;
typedef __attribute__((address_space(3))) unsigned int lds_u32;
typedef const __attribute__((address_space(1))) unsigned int glb_u32;

__device__ __forceinline__ void gll16(const void* g, void* l) {
    __builtin_amdgcn_global_load_lds((glb_u32*)g, (lds_u32*)l, 16, 0, 0);
}

__device__ __forceinline__ unsigned short f2bf(float f) {
    unsigned int u = __float_as_uint(f);
    u += 0x7FFFu + ((u >> 16) & 1u);   // RNE
    return (unsigned short)(u >> 16);
}

__device__ __forceinline__ float fast_tanh(float x) {
    x = fminf(fmaxf(x, -9.0f), 9.0f);
    float t = __builtin_amdgcn_exp2f(x * 2.8853900817779268f);
    return (t - 1.0f) * __builtin_amdgcn_rcpf(t + 1.0f);
}

__global__ void zero_k(int* __restrict__ ctrl) {
    if (threadIdx.x < 16) ctrl[threadIdx.x] = 0;
}

// Parallel histogram: wave-aggregated, 4 atomics/wave max.
__global__ void count_k(const int* __restrict__ cmd, int* __restrict__ ctrl) {
    int i = blockIdx.x * 256 + threadIdx.x;
    int e = cmd[i] & 3;
    int lane = threadIdx.x & 63;
#pragma unroll
    for (int ee = 0; ee < 4; ++ee) {
        unsigned long long mask = __ballot(e == ee);
        int leader = __ffsll((unsigned long long)mask) - 1;
        if (mask && lane == leader)
            atomicAdd(&ctrl[ee], __popcll(mask));
    }
}

// Tiny: build BOTH tile plans (128-row kept for compatibility, 64-row used
// by all GEMMs) + segment bases + zero scatter cursors. Padding stays
// 128-granular, so every 64-row tile is full.
__global__ void plan_k(int* __restrict__ ctrl,
                       int* __restrict__ t64E, int* __restrict__ t64B,
                       int* __restrict__ t128E, int* __restrict__ t128B) {
    if (threadIdx.x == 0) {
        int P = 0, n128 = 0, n64 = 0;
        for (int e = 0; e < 4; ++e) {
            ctrl[4 + e] = 0;          // scatter cursors
            ctrl[8 + e] = P;
            int t128 = (ctrl[e] + 127) >> 7;
            for (int t = 0; t < t128; ++t) {
                t128E[n128] = e; t128B[n128] = P + t * 128; ++n128;
            }
            for (int t = 0; t < t128 * 2; ++t) {
                t64E[n64] = e; t64B[n64] = P + t * 64; ++n64;
            }
            P += t128 * 128;
        }
        ctrl[12] = P;                 // total padded rows
        ctrl[13] = n128;              // 128-row tiles (<= 132)
        ctrl[14] = n64;               // 64-row tiles (<= 264)
    }
}

// Wave-aggregated scatter: one atomicAdd(popcount) per wave per expert.
__global__ void scatter_k(const int* __restrict__ cmd, int* __restrict__ ctrl,
                          int* __restrict__ perm) {
    int i = blockIdx.x * 256 + threadIdx.x;
    int e = cmd[i] & 3;
    int lane = threadIdx.x & 63;
#pragma unroll
    for (int ee = 0; ee < 4; ++ee) {
        unsigned long long mask = __ballot(e == ee);
        if (e == ee) {
            int leader = __ffsll((unsigned long long)mask) - 1;
            int rank = __popcll(mask & ((1ull << lane) - 1ull));
            int wbase = 0;
            if (lane == leader)
                wbase = atomicAdd(&ctrl[4 + ee], __popcll(mask));
            wbase = __builtin_amdgcn_readfirstlane(wbase);
            perm[ctrl[8 + ee] + wbase + rank] = i;
        }
    }
}

// Fused prep: blocks [0,8192) transpose+convert weights (packed uint writes);
// blocks [8192,12416) gather x -> permuted bf16 xp and fill pad perm entries.
__global__ __launch_bounds__(256) void prep_data_k(
    const float* __restrict__ W1, const float* __restrict__ W2,
    const float* __restrict__ W3, unsigned short* __restrict__ Wt1,
    unsigned short* __restrict__ Wt2, unsigned short* __restrict__ Wt3,
    const float* __restrict__ x, unsigned short* __restrict__ xp,
    int* __restrict__ perm, const int* __restrict__ ctrl)
{
    int b = blockIdx.x;
    if (b < 8192) {
        int e = b >> 11, r = b & 2047;
        const float* W; unsigned short* Wt; int KD, ND, kt, nt;
        if (r < 512)       { W = W1; Wt = Wt1; KD = 512;  ND = 1024; kt = r & 15;           nt = r >> 4; }
        else if (r < 1536) { W = W2; Wt = Wt2; KD = 1024; ND = 1024; kt = (r - 512) & 31;   nt = (r - 512) >> 5; }
        else               { W = W3; Wt = Wt3; KD = 1024; ND = 512;  kt = (r - 1536) & 31;  nt = (r - 1536) >> 5; }
        __shared__ float t[32][33];
        size_t base = (size_t)e * KD * ND;
        int k0 = kt * 32, n0 = nt * 32;
        int tx = threadIdx.x & 31, ty = threadIdx.x >> 5;
#pragma unroll
        for (int s = 0; s < 4; ++s)
            t[ty + s * 8][tx] = W[base + (size_t)(k0 + ty + s * 8) * ND + n0 + tx];
        __syncthreads();
        int tx2 = (threadIdx.x & 15) * 2, ny = threadIdx.x >> 4;
#pragma unroll
        for (int s = 0; s < 2; ++s) {
            int n = ny + s * 16;
            unsigned int v = (unsigned)f2bf(t[tx2][n])
                           | ((unsigned)f2bf(t[tx2 + 1][n]) << 16);
            *(unsigned int*)&Wt[base + (size_t)(n0 + n) * KD + k0 + tx2] = v;
        }
    } else {
        int g = b - 8192;
        int p = g * 4 + (int)(threadIdx.x >> 6);
        if (p >= ctrl[12]) return;
        int lane = threadIdx.x & 63;
        int e = (p >= ctrl[9]) + (p >= ctrl[10]) + (p >= ctrl[11]);
        int segBase = ctrl[8 + e];
        int src;
        if (p < segBase + ctrl[e]) {
            src = perm[p];
        } else {
            src = perm[segBase];              // duplicate a valid same-expert row
            if (lane == 0) perm[p] = src;     // so gemm3 scatter-epilogue is safe
        }
        const float* xr = x + (size_t)src * DIN + lane * 8;
        float4 a = *(const float4*)xr;
        float4 c = *(const float4*)(xr + 4);
        uint4 o;
        o.x = (unsigned)f2bf(a.x) | ((unsigned)f2bf(a.y) << 16);
        o.y = (unsigned)f2bf(a.z) | ((unsigned)f2bf(a.w) << 16);
        o.z = (unsigned)f2bf(c.x) | ((unsigned)f2bf(c.y) << 16);
        o.w = (unsigned)f2bf(c.z) | ((unsigned)f2bf(c.w) << 16);
        *(uint4*)(xp + (size_t)p * DIN + lane * 8) = o;
    }
}

// Grouped GEMM: C = act(A @ Wt[e]^T + b[e]). BM/BN template, BK=64, 256 thr
// = 4 waves (2x2 quadrants: wave tile (BM/2) x (BN/2); MI=BM/32, NI=BN/32
// 16x16x32 frags, 2 k-halves). Single buffer, 2 barriers per K-step.
// Chunk-XOR involution: LDS slot s of row r holds global 16B-chunk
// (s ^ (r&7)); ds_read XORs the same (call bases are 32-row multiples so
// row&7 == tr&7). gll16 LDS dest stays tid*16B-linear per call.
// Chunked XCD swizzle: grid = NTILES*PN (divisible by 8), XCD x covers
// tiles [CH*x, CH*(x+1)) x all panels, CH = NTILES/8.
template<int K, int N, int BM, int BN, int NTILES, int PN, int CIDX,
         int ACT, bool SCATTER_OUT>
__global__ __launch_bounds__(256) void gemm_k(
    const unsigned short* __restrict__ A, const unsigned short* __restrict__ Bt,
    const float* __restrict__ bias, void* __restrict__ Outp,
    const int* __restrict__ ctrl, const int* __restrict__ tileExpert,
    const int* __restrict__ tileBase, const int* __restrict__ perm)
{
    constexpr int MI = BM / 32;               // A frags per wave (4 or 2)
    constexpr int NI = BN / 32;               // B frags per wave (4)
    constexpr int ACALLS = BM / 32;
    constexpr int BCALLS = BN / 32;
    const int l = (int)blockIdx.x + NTILES * (int)blockIdx.y;
    const int swz = (l & 7) * ((NTILES / 8) * PN) + (l >> 3);
    const int tile = swz / PN;                // PN pow2 -> shift
    const int panel = swz & (PN - 1);
    if (tile >= ctrl[CIDX]) return;
    const int e = tileExpert[tile];
    const int rowBase = tileBase[tile];
    const int n0 = panel * BN;

    __shared__ unsigned short Als[BM * 64];   // 16 or 8 KB
    __shared__ unsigned short Bls[BN * 64];   // 16 KB

    const int tid = threadIdx.x;
    const int lane = tid & 63;
    const int w = tid >> 6;
    const int wm = w >> 1, wn = w & 1;
    const int lr = lane & 15, lh = lane >> 4;

    f32x4 acc[MI][NI] = {};

    // Staging: thread t -> row tr (within 32-row call-block), chunk-slot tc.
    const int tr = tid >> 3;                  // 0..31
    const int tc = tid & 7;                   // chunk slot 0..7
    const int cs = (tc ^ (tr & 7)) * 8;       // source ushort offset in row
    const unsigned short* As = A + (size_t)(rowBase + tr) * K + cs;
    const unsigned short* Bs = Bt + ((size_t)e * N + n0 + tr) * K + cs;
    const int ldst = tr * 64 + tc * 8;        // ushort idx; byte == tid*16

    constexpr int NK = K / 64;
    for (int kq = 0; kq < NK; ++kq) {
        const int k0 = kq * 64;
        __syncthreads();                      // prior reads of buffer done
#pragma unroll
        for (int j = 0; j < ACALLS; ++j)
            gll16(As + (size_t)(j * 32) * K + k0, &Als[j * 2048 + ldst]);
#pragma unroll
        for (int j = 0; j < BCALLS; ++j)
            gll16(Bs + (size_t)(j * 32) * K + k0, &Bls[j * 2048 + ldst]);
        __syncthreads();                      // drains vmcnt before release
#pragma unroll
        for (int kk = 0; kk < 2; ++kk) {
            const int ksl = ((kk * 4 + lh) ^ (lr & 7)) * 8;   // swizzled read
            bf16x8 afr[MI], bfr[NI];
#pragma unroll
            for (int mi = 0; mi < MI; ++mi)
                afr[mi] = *(const bf16x8*)&Als[(wm * (BM / 2) + mi * 16 + lr) * 64 + ksl];
#pragma unroll
            for (int ni = 0; ni < NI; ++ni)
                bfr[ni] = *(const bf16x8*)&Bls[(wn * (BN / 2) + ni * 16 + lr) * 64 + ksl];
#pragma unroll
            for (int mi = 0; mi < MI; ++mi)
#pragma unroll
                for (int ni = 0; ni < NI; ++ni)
                    acc[mi][ni] = __builtin_amdgcn_mfma_f32_16x16x32_bf16(
                        afr[mi], bfr[ni], acc[mi][ni], 0, 0, 0);
        }
    }

    float bv[NI];
    int colv[NI];
#pragma unroll
    for (int ni = 0; ni < NI; ++ni) {
        colv[ni] = n0 + wn * (BN / 2) + ni * 16 + lr;
        bv[ni] = bias[e * N + colv[ni]];
    }
#pragma unroll
    for (int mi = 0; mi < MI; ++mi) {
#pragma unroll
        for (int r = 0; r < 4; ++r) {
            int rowL = wm * (BM / 2) + mi * 16 + lh * 4 + r;  // C/D row map
            int gRow = rowBase + rowL;
            int orow = SCATTER_OUT ? perm[gRow] : gRow;
#pragma unroll
            for (int ni = 0; ni < NI; ++ni) {
                float v = acc[mi][ni][r] + bv[ni];
                if (ACT == 0) v = fmaxf(v, 0.0f);
                else          v = fast_tanh(v);
                if (SCATTER_OUT)
                    ((float*)Outp)[(size_t)orow * N + colv[ni]] = v;
                else
                    ((unsigned short*)Outp)[(size_t)orow * N + colv[ni]] = f2bf(v);
            }
        }
    }
}

extern "C" void kernel_launch(void* const* d_in, const int* in_sizes, int n_in,
                              void* d_out, int out_size, void* d_ws, size_t ws_size,
                              hipStream_t stream) {
    const float* x  = (const float*)d_in[0];
    const int*   cmd= (const int*)d_in[1];
    const float* W1 = (const float*)d_in[2];
    const float* b1 = (const float*)d_in[3];
    const float* W2 = (const float*)d_in[4];
    const float* b2 = (const float*)d_in[5];
    const float* W3 = (const float*)d_in[6];
    const float* b3 = (const float*)d_in[7];
    float* out = (float*)d_out;

    char* w = (char*)d_ws;
    int* ctrl  = (int*)w;
    int* t64E  = ctrl + 64;     // 264
    int* t64B  = ctrl + 384;    // 264
    int* t128E = ctrl + 704;    // 136
    int* t128B = ctrl + 896;    // 136
    int* perm  = ctrl + 1088;   // 16896 ints, ends < 128KB
    unsigned short* Wt1 = (unsigned short*)(w + 131072);
    unsigned short* Wt2 = (unsigned short*)(w + 131072 + 4194304);
    unsigned short* Wt3 = (unsigned short*)(w + 131072 + 12582912);
    unsigned short* h1  = (unsigned short*)(w + 131072 + 16777216);
    unsigned short* h2  = h1 + (size_t)16896 * HID;       // 34.6 MB each
    unsigned short* xp  = h2;                             // aliases h2 (WAR-safe)

    zero_k<<<1, 64, 0, stream>>>(ctrl);
    count_k<<<B_N / 256, 256, 0, stream>>>(cmd, ctrl);
    plan_k<<<1, 64, 0, stream>>>(ctrl, t64E, t64B, t128E, t128B);
    scatter_k<<<B_N / 256, 256, 0, stream>>>(cmd, ctrl, perm);
    prep_data_k<<<8192 + 4224, 256, 0, stream>>>(W1, W2, W3, Wt1, Wt2, Wt3,
                                                 x, xp, perm, ctrl);

    // gemm1: 64x128, 2112 blocks, 24KB LDS (6 blocks/CU)
    gemm_k<DIN, HID, 64, 128, MAXT64, 8, 14, 0, false>
        <<<dim3(MAXT64, 8), 256, 0, stream>>>(
        xp, Wt1, b1, h1, ctrl, t64E, t64B, perm);
    // gemm2: 64x128, 2112 blocks
    gemm_k<HID, HID, 64, 128, MAXT64, 8, 14, 0, false>
        <<<dim3(MAXT64, 8), 256, 0, stream>>>(
        h1, Wt2, b2, h2, ctrl, t64E, t64B, perm);
    // gemm3: 64x128, 1056 blocks
    gemm_k<HID, DOUT, 64, 128, MAXT64, 4, 14, 1, true>
        <<<dim3(MAXT64, 4), 256, 0, stream>>>(
        h2, Wt3, b3, out, ctrl, t64E, t64B, perm);
}